// Round 1
// baseline (4296.854 us; speedup 1.0000x reference)
//
#include <hip/hip_runtime.h>
#include <cstdint>
#include <cstddef>

typedef __attribute__((ext_vector_type(8))) short short8;
typedef __attribute__((ext_vector_type(4))) short short4v;
typedef __attribute__((ext_vector_type(4))) float float4v;

typedef __attribute__((address_space(3))) uint32_t lds_u32;
typedef const __attribute__((address_space(1))) uint32_t gl_u32;

__device__ __forceinline__ short f2bf(float f) {
    union { float f; uint32_t u; } v; v.f = f;
    uint32_t r = v.u + 0x7fffu + ((v.u >> 16) & 1u);
    return (short)(r >> 16);
}
__device__ __forceinline__ float bf2f(short s) {
    union { uint32_t u; float f; } v; v.u = ((uint32_t)(uint16_t)s) << 16;
    return v.f;
}
__device__ __forceinline__ float sigmoidf_(float z) {
    return 1.0f / (1.0f + __expf(-z));
}

// ---------------------------------------------------------------------------
// Prep: x (32768x1024 f32) -> bf16 into Xcat[:, 0:1024] (row stride 1280)
// ---------------------------------------------------------------------------
__global__ __launch_bounds__(256) void xconvert_kernel(const float* __restrict__ x,
                                                       short* __restrict__ Xcat) {
    size_t i = ((size_t)blockIdx.x * 256 + threadIdx.x) * 4;
    size_t r = i >> 10, c = i & 1023;
    float4v v = *(const float4v*)(x + i);
    short4v o;
#pragma unroll
    for (int j = 0; j < 4; ++j) o[j] = f2bf(v[j]);
    *(short4v*)(Xcat + r * 1280 + c) = o;
}

// ---------------------------------------------------------------------------
// Prep: W3b = bf16([Wi; Wf[:, :1024]; Wu[:, :1024]]) (768x1024)
//       Wob = bf16(Wo) (1024x1280)
// ---------------------------------------------------------------------------
__global__ __launch_bounds__(256) void wconvert_kernel(const float* __restrict__ Wi,
                                                       const float* __restrict__ Wf,
                                                       const float* __restrict__ Wu,
                                                       const float* __restrict__ Wo,
                                                       short* __restrict__ W3b,
                                                       short* __restrict__ Wob) {
    int i = blockIdx.x * 256 + threadIdx.x;
    if (i < 768 * 1024) {
        int n = i >> 10, k = i & 1023;
        const float* src = (n < 256) ? (Wi + (size_t)n * 1024 + k)
                         : (n < 512) ? (Wf + (size_t)(n - 256) * 1280 + k)
                                     : (Wu + (size_t)(n - 512) * 1280 + k);
        W3b[i] = f2bf(*src);
    } else {
        int j = i - 768 * 1024;   // 0 .. 1024*1280-1
        Wob[j] = f2bf(Wo[j]);
    }
}

// ---------------------------------------------------------------------------
// Tiled bf16 MFMA GEMM: C[gr][gc] = sum_k A[gr][k]*B[gc][k]
// 128x128 tile, BK=32, 256 threads (4 waves, 2x2), global_load_lds staging.
// EPI=1: bias + silu(first 256 cols), bf16 out scattered to xmfu[t][b][n]
// EPI=2: + bo[gc] + x[gr][gc] residual, fp32 out to d_out
// ---------------------------------------------------------------------------
template <int EPI>
__global__ __launch_bounds__(256) void gemm_bt(const short* __restrict__ A,
                                               const short* __restrict__ Bmat,
                                               const int K, const int lda,
                                               const float* __restrict__ bias1,
                                               const float* __restrict__ bias2,
                                               const float* __restrict__ bias3,
                                               const float* __restrict__ xres,
                                               float* __restrict__ outf,
                                               short* __restrict__ outb) {
    __shared__ __align__(16) short As[4096];
    __shared__ __align__(16) short Bs[4096];

    const int tid = threadIdx.x;
    const int lane = tid & 63;
    const int wv = tid >> 6;
    const int wm = wv >> 1, wn = wv & 1;
    const int row15 = lane & 15;
    const int q = lane >> 4;
    const int tileM = blockIdx.x * 128;
    const int tileN = blockIdx.y * 128;

    float4v acc[4][4];
#pragma unroll
    for (int i = 0; i < 4; ++i)
#pragma unroll
        for (int j = 0; j < 4; ++j) acc[i][j] = {0.f, 0.f, 0.f, 0.f};

    // staging: chunk c = (round*256 + tid); row = c>>2, k8 = (c&3)*8 ; LDS byte c*16
    const short* aG = A + (size_t)(tileM + (tid >> 2)) * lda + (tid & 3) * 8;
    const short* bG = Bmat + (size_t)(tileN + (tid >> 2)) * K + (tid & 3) * 8;
    const size_t aStep = (size_t)64 * lda;
    const size_t bStep = (size_t)64 * K;

    lds_u32* AsL = (lds_u32*)As;
    lds_u32* BsL = (lds_u32*)Bs;
    const int base1 = wv * 256;          // dwords: wave-uniform LDS base, HW adds lane*16
    const int base2 = 1024 + wv * 256;

    for (int kt = 0; kt < K; kt += 32) {
        __builtin_amdgcn_global_load_lds((gl_u32*)aG,           AsL + base1, 16, 0, 0);
        __builtin_amdgcn_global_load_lds((gl_u32*)(aG + aStep), AsL + base2, 16, 0, 0);
        __builtin_amdgcn_global_load_lds((gl_u32*)bG,           BsL + base1, 16, 0, 0);
        __builtin_amdgcn_global_load_lds((gl_u32*)(bG + bStep), BsL + base2, 16, 0, 0);
        aG += 32; bG += 32;
        __syncthreads();

        short8 af[4], bf8[4];
#pragma unroll
        for (int mt = 0; mt < 4; ++mt)
            af[mt] = *(const short8*)(As + (wm * 64 + mt * 16 + row15) * 32 + q * 8);
#pragma unroll
        for (int nt = 0; nt < 4; ++nt)
            bf8[nt] = *(const short8*)(Bs + (wn * 64 + nt * 16 + row15) * 32 + q * 8);
#pragma unroll
        for (int mt = 0; mt < 4; ++mt)
#pragma unroll
            for (int nt = 0; nt < 4; ++nt)
                acc[mt][nt] = __builtin_amdgcn_mfma_f32_16x16x32_bf16(af[mt], bf8[nt], acc[mt][nt], 0, 0, 0);
        __syncthreads();
    }

#pragma unroll
    for (int mt = 0; mt < 4; ++mt) {
#pragma unroll
        for (int nt = 0; nt < 4; ++nt) {
#pragma unroll
            for (int r = 0; r < 4; ++r) {
                const int gr = tileM + wm * 64 + mt * 16 + q * 4 + r;
                const int gc = tileN + wn * 64 + nt * 16 + row15;
                float v = acc[mt][nt][r];
                if (EPI == 1) {
                    float bias = (gc < 256) ? bias1[gc] : (gc < 512) ? bias2[gc - 256] : bias3[gc - 512];
                    float z = v + bias;
                    if (gc < 256) z = z * sigmoidf_(z);   // silu for xm
                    const int b = gr >> 11, t = gr & 2047;
                    outb[((size_t)t * 16 + b) * 768 + gc] = f2bf(z);
                } else {
                    const size_t idx = (size_t)gr * 1024 + gc;
                    outf[idx] = v + bias1[gc] + xres[idx];
                }
            }
        }
    }
}

// ---------------------------------------------------------------------------
// Sequential scan: ONE workgroup (16 waves), all 16 batches via MFMA M=16.
// WfH/WuH live in registers as B-fragments; h round-trips LDS in A-frag order.
// Writes H (bf16) into Xcat[:, 1024:1280) and h_final (fp32) to hfinal.
// ---------------------------------------------------------------------------
__global__ __launch_bounds__(1024) void scan_kernel(const float* __restrict__ Wfp,
                                                    const float* __restrict__ Wup,
                                                    const short* __restrict__ xmfu,
                                                    short* __restrict__ Xcat,
                                                    float* __restrict__ hfinal) {
    __shared__ __align__(16) short hb[4096];   // h bf16 in A-fragment order [ks][lane][8]
    __shared__ float fu[8192];                 // f (0..4095) and u (4096..8191): [b][n]

    const int tid = threadIdx.x;
    const int lane = tid & 63;
    const int w = tid >> 6;        // wave 0..15
    const int sel = w >> 3;        // 0 = f (Wf), 1 = u (Wu)
    const int n0 = (w & 7) * 32;   // this wave's N-slice
    const int row15 = lane & 15;
    const int q = lane >> 4;

    for (int i = tid; i < 4096; i += 1024) hb[i] = 0;

    // B-fragments: B[k][n] = WH[n][1024+k]; lane holds n = n0+nt*16+(lane&15),
    // k = ks*32 + q*8 + j. Held in registers for the whole scan.
    const float* WH = sel ? Wup : Wfp;
    short8 bfrag[8][2];
#pragma unroll
    for (int ks = 0; ks < 8; ++ks)
#pragma unroll
        for (int nt = 0; nt < 2; ++nt) {
            const float* src = WH + (size_t)(n0 + nt * 16 + row15) * 1280 + 1024 + ks * 32 + q * 8;
            short8 v;
#pragma unroll
            for (int j = 0; j < 8; ++j) v[j] = f2bf(src[j]);
            bfrag[ks][nt] = v;
        }

    // persistent fp32 recurrence state: thread (w, lane) owns h[b=w][lane + 64*i]
    float hreg[4] = {0.f, 0.f, 0.f, 0.f};

    // register prefetch of this lane's xf/xu logit biases and xm values (t=0)
    float zb[8], xmv[4];
#pragma unroll
    for (int nt = 0; nt < 2; ++nt)
#pragma unroll
        for (int r = 0; r < 4; ++r)
            zb[nt * 4 + r] = bf2f(xmfu[(size_t)(q * 4 + r) * 768 + 256 + sel * 256 + n0 + nt * 16 + row15]);
#pragma unroll
    for (int i = 0; i < 4; ++i)
        xmv[i] = bf2f(xmfu[(size_t)w * 768 + lane + 64 * i]);

    __syncthreads();

    for (int t = 0; t < 2048; ++t) {
        // prefetch next step's values (clamped at the end; overlaps MFMA phase)
        const int tn = (t < 2047) ? (t + 1) : 2047;
        const size_t nb = (size_t)tn * 12288;
        float zbn[8], xmvn[4];
#pragma unroll
        for (int nt = 0; nt < 2; ++nt)
#pragma unroll
            for (int r = 0; r < 4; ++r)
                zbn[nt * 4 + r] = bf2f(xmfu[nb + (q * 4 + r) * 768 + 256 + sel * 256 + n0 + nt * 16 + row15]);
#pragma unroll
        for (int i = 0; i < 4; ++i)
            xmvn[i] = bf2f(xmfu[nb + w * 768 + lane + 64 * i]);

        // MFMA phase: logits = h @ WH^T for this wave's 32 output columns
        float4v a0 = {0.f, 0.f, 0.f, 0.f}, a1 = {0.f, 0.f, 0.f, 0.f};
#pragma unroll
        for (int ks = 0; ks < 8; ++ks) {
            short8 af = *(const short8*)(hb + ks * 512 + lane * 8);
            a0 = __builtin_amdgcn_mfma_f32_16x16x32_bf16(af, bfrag[ks][0], a0, 0, 0, 0);
            a1 = __builtin_amdgcn_mfma_f32_16x16x32_bf16(af, bfrag[ks][1], a1, 0, 0, 0);
        }
        // C/D: batch = q*4 + r, col = nt*16 + row15. sigmoid -> fu LDS.
#pragma unroll
        for (int nt = 0; nt < 2; ++nt) {
            const int n = n0 + nt * 16 + row15;
#pragma unroll
            for (int r = 0; r < 4; ++r) {
                const int b = q * 4 + r;
                float z = (nt ? a1[r] : a0[r]) + zb[nt * 4 + r];
                fu[sel * 4096 + b * 256 + n] = sigmoidf_(z);
            }
        }
        __syncthreads();

        // elementwise phase: h_new = f*h + u*xm ; rewrite hb in A-frag order
#pragma unroll
        for (int i = 0; i < 4; ++i) {
            const int m = lane + 64 * i;
            float f = fu[w * 256 + m];
            float u = fu[4096 + w * 256 + m];
            float hn = f * hreg[i] + u * xmv[i];
            hreg[i] = hn;
            short hnb = f2bf(hn);
            hb[((m >> 5) * 64 + ((m >> 3) & 3) * 16 + w) * 8 + (m & 7)] = hnb;
            Xcat[(size_t)(w * 2048 + t) * 1280 + 1024 + m] = hnb;
        }
#pragma unroll
        for (int k = 0; k < 8; ++k) zb[k] = zbn[k];
#pragma unroll
        for (int i = 0; i < 4; ++i) xmv[i] = xmvn[i];
        __syncthreads();
    }

#pragma unroll
    for (int i = 0; i < 4; ++i) hfinal[w * 256 + lane + 64 * i] = hreg[i];
}

// ---------------------------------------------------------------------------
extern "C" void kernel_launch(void* const* d_in, const int* in_sizes, int n_in,
                              void* d_out, int out_size, void* d_ws, size_t ws_size,
                              hipStream_t stream) {
    const float* x  = (const float*)d_in[0];
    const float* Wi = (const float*)d_in[1];
    const float* bi = (const float*)d_in[2];
    const float* Wf = (const float*)d_in[3];
    const float* bf = (const float*)d_in[4];
    const float* Wu = (const float*)d_in[5];
    const float* bu = (const float*)d_in[6];
    const float* Wo = (const float*)d_in[7];
    const float* bo = (const float*)d_in[8];
    float* out = (float*)d_out;   // 33554432 outs + 4096 h_final

    char* ws = (char*)d_ws;
    short* Xcat = (short*)ws;                                  // 32768*1280*2 = 83,886,080 B
    short* xmfu = (short*)(ws + 83886080ULL);                  // [t][b][768]: 50,331,648 B
    short* W3b  = (short*)(ws + 83886080ULL + 50331648ULL);    // 768*1024*2
    short* Wob  = (short*)(ws + 83886080ULL + 50331648ULL + 1572864ULL); // 1024*1280*2

    xconvert_kernel<<<dim3(32768), dim3(256), 0, stream>>>(x, Xcat);
    wconvert_kernel<<<dim3(8192), dim3(256), 0, stream>>>(Wi, Wf, Wu, Wo, W3b, Wob);
    // xm/xf/xu: (32768 x 768) = Xcat[:, :1024] @ W3b^T (+bias, silu on xm)
    gemm_bt<1><<<dim3(256, 6), dim3(256), 0, stream>>>(Xcat, W3b, 1024, 1280,
                                                       bi, bf, bu, nullptr, nullptr, xmfu);
    // sequential recurrence (writes H into Xcat[:, 1024:1280) and h_final)
    scan_kernel<<<dim3(1), dim3(1024), 0, stream>>>(Wf, Wu, xmfu, Xcat, out + 33554432);
    // out = x + Xcat @ Wo^T + bo   (covers x@Wo[:,:d]^T + H@WoH^T)
    gemm_bt<2><<<dim3(256, 8), dim3(256), 0, stream>>>(Xcat, Wob, 1280, 1280,
                                                       bo, nullptr, nullptr, x, out, nullptr);
}